// Round 3
// baseline (101.463 us; speedup 1.0000x reference)
//
#include <hip/hip_runtime.h>

#define HH 224
#define WW 224

// out[b,y,x,c] = sbp[b, Yi, Xi, c]
//   Yi = int((y + dy) mod H)  (jnp.remainder semantics), clamped to H-1
//   Xi = int((x + dx) mod W), clamped to W-1
//   sbp[y,x,c] = 0 on the 1-px border; interior:
//     0.25*(img[y-1,x-1,c]+img[y-1,x+1,c]+img[y+1,x-1,c]+img[y+1,x+1,c])
__global__ __launch_bounds__(256) void bilinear_gather_kernel(
    const float* __restrict__ x, float* __restrict__ out, int total /* B*H*W */) {
    int i = blockIdx.x * blockDim.x + threadIdx.x;
    if (i >= total) return;

    int px = i % WW;
    int t  = i / WW;
    int py = t % HH;
    int b  = t / HH;

    const float* pix = x + (size_t)i * 5;
    float dx = pix[3];
    float dy = pix[4];

    // jnp.remainder: trunc fmod, then +W if result negative (W>0 here).
    float rx = fmodf((float)px + dx, (float)WW);
    if (rx < 0.f) rx += (float)WW;   // can round to exactly 224.0
    float ry = fmodf((float)py + dy, (float)HH);
    if (ry < 0.f) ry += (float)HH;

    int xi = (int)rx; if (xi > WW - 1) xi = WW - 1;  // JAX clamps OOB gather
    int yi = (int)ry; if (yi > HH - 1) yi = HH - 1;

    float r = 0.f, g = 0.f, bb = 0.f;
    if (xi >= 1 && xi <= WW - 2 && yi >= 1 && yi <= HH - 2) {
        const float* base = x + (size_t)b * HH * WW * 5;
        const float* p00 = base + ((size_t)(yi - 1) * WW + (xi - 1)) * 5;
        const float* p01 = base + ((size_t)(yi - 1) * WW + (xi + 1)) * 5;
        const float* p10 = base + ((size_t)(yi + 1) * WW + (xi - 1)) * 5;
        const float* p11 = base + ((size_t)(yi + 1) * WW + (xi + 1)) * 5;
        r  = 0.25f * (p00[0] + p01[0] + p10[0] + p11[0]);
        g  = 0.25f * (p00[1] + p01[1] + p10[1] + p11[1]);
        bb = 0.25f * (p00[2] + p01[2] + p10[2] + p11[2]);
    }
    float* o = out + (size_t)i * 3;
    o[0] = r;
    o[1] = g;
    o[2] = bb;
}

extern "C" void kernel_launch(void* const* d_in, const int* in_sizes, int n_in,
                              void* d_out, int out_size, void* d_ws, size_t ws_size,
                              hipStream_t stream) {
    const float* x = (const float*)d_in[0];
    float* out = (float*)d_out;
    int total = in_sizes[0] / 5;  // B*H*W
    int blocks = (total + 255) / 256;
    bilinear_gather_kernel<<<blocks, 256, 0, stream>>>(x, out, total);
}

// Round 4
// 46.246 us; speedup vs baseline: 2.1940x; 2.1940x over previous
//
#include <hip/hip_runtime.h>

#define HH 224
#define WW 224
#define NXCD 8

// out[b,y,x,c] = sbp[b, Yi, Xi, c]
//   Yi = int((y + dy) mod H)  (jnp.remainder semantics), clamped to H-1
//   Xi = int((x + dx) mod W), clamped to W-1
//   sbp[y,x,c] = 0 on the 1-px border; interior:
//     0.25*(img[y-1,x-1,c]+img[y-1,x+1,c]+img[y+1,x-1,c]+img[y+1,x+1,c])
__global__ __launch_bounds__(256) void bilinear_gather_kernel(
    const float* __restrict__ x, float* __restrict__ out, int total /* B*H*W */,
    int nwg) {
    // XCD-aware bijective swizzle (m204 form): physical block p lands on XCD
    // p%8; remap so each XCD processes a CONTIGUOUS slab of logical blocks.
    // Then rows r-1, r, r+1 (which share gather lines) live in one L2.
    int p = blockIdx.x;
    int xcd = p % NXCD;
    int idx = p / NXCD;
    int q = nwg / NXCD;
    int r = nwg % NXCD;
    int lb = (xcd < r ? xcd * (q + 1) : r * (q + 1) + (xcd - r) * q) + idx;

    int i = lb * blockDim.x + threadIdx.x;
    if (i >= total) return;

    int px = i % WW;
    int t  = i / WW;
    int py = t % HH;
    int b  = t / HH;

    const float* pix = x + (size_t)i * 5;
    float dx = pix[3];
    float dy = pix[4];

    // jnp.remainder: trunc fmod, then +W if result negative (W>0 here).
    float rx = fmodf((float)px + dx, (float)WW);
    if (rx < 0.f) rx += (float)WW;   // can round to exactly 224.0
    float ry = fmodf((float)py + dy, (float)HH);
    if (ry < 0.f) ry += (float)HH;

    int xi = (int)rx; if (xi > WW - 1) xi = WW - 1;  // JAX clamps OOB gather
    int yi = (int)ry; if (yi > HH - 1) yi = HH - 1;

    float r0 = 0.f, g0 = 0.f, b0 = 0.f;
    if (xi >= 1 && xi <= WW - 2 && yi >= 1 && yi <= HH - 2) {
        const float* base = x + (size_t)b * HH * WW * 5;
        const float* p00 = base + ((size_t)(yi - 1) * WW + (xi - 1)) * 5;
        const float* p01 = base + ((size_t)(yi - 1) * WW + (xi + 1)) * 5;
        const float* p10 = base + ((size_t)(yi + 1) * WW + (xi - 1)) * 5;
        const float* p11 = base + ((size_t)(yi + 1) * WW + (xi + 1)) * 5;
        r0 = 0.25f * (p00[0] + p01[0] + p10[0] + p11[0]);
        g0 = 0.25f * (p00[1] + p01[1] + p10[1] + p11[1]);
        b0 = 0.25f * (p00[2] + p01[2] + p10[2] + p11[2]);
    }
    float* o = out + (size_t)i * 3;
    o[0] = r0;
    o[1] = g0;
    o[2] = b0;
}

extern "C" void kernel_launch(void* const* d_in, const int* in_sizes, int n_in,
                              void* d_out, int out_size, void* d_ws, size_t ws_size,
                              hipStream_t stream) {
    const float* x = (const float*)d_in[0];
    float* out = (float*)d_out;
    int total = in_sizes[0] / 5;  // B*H*W
    int blocks = (total + 255) / 256;
    bilinear_gather_kernel<<<blocks, 256, 0, stream>>>(x, out, total, blocks);
}